// Round 7
// baseline (182.765 us; speedup 1.0000x reference)
//
#include <hip/hip_runtime.h>

// Fused Xcodec2 ISTFT: B=16, FREQ=513, FRAMES=2048, n_fft=1024, hop=256, win=1024
// out: [16, 1, 524288] fp32
//
// One-frame-per-wave version, round 7: table-free, minimal LDS traffic.
//  - Complex math as ext_vector float2 (v2f) -> packed v_pk_add/fma_f32.
//  - Spectra staged coalesced global -> frame-major LDS rows; invalid
//    frame-pairs zeroed (validity pair-aligned).
//  - Per-wave 512-pt radix-8 Stockham FFT in the wave's own LDS row;
//    wave-local lgkmcnt fences; Z slots XOR-swizzled (conflict-free).
//  - NO LDS tables: PRE[j+64m] = e^{i pi j/512} * e^{i pi m/8} (sincos +
//    8 constant cmuls); tw1 = pb^2; running-product twiddles (2 v2f live).
//  - Window applied at OLA in registers: angle = pi*me0/256 + jj*pi/2, the
//    jj part is i^jj (sign/swap only) -> 1 sincos + 1 const cmul per lane
//    gives all 8 window values; me0 identical across both output rows.
//  - Frame rows written as raw interleaved (even,odd) float2 pairs (8 b64),
//    OLA reads one b64 tap per frame (4 taps) -> LDS instr cut ~30%.
//  - ifft norm (0.5/512) and COLA interior envelope (2/3) folded into the
//    window constant; edges multiply by 1.5/e (exact global win).
//  - LDS = 16*515 v2f = 65.9 KB -> 2 WG/CU, 32 waves (cap). 2 barriers.

#define B_      16
#define FREQ_   513
#define FRAMES_ 2048
#define PAD_    384
#define T_OUT_  524288
#define HPW     12           // useful hops per WG
#define SPW     3072         // output samples per WG
#define NCHUNK  171          // ceil(T_OUT/SPW)

#define FS2     515          // v2f stride of one frame row in S
#define LDS2N   8240         // 16*515 v2f = 65,920 B

#define LGKM_SYNC() asm volatile("s_waitcnt lgkmcnt(0)" ::: "memory")

typedef float v2f __attribute__((ext_vector_type(2)));

__device__ __forceinline__ v2f mk2(float a, float b) { v2f r; r.x = a; r.y = b; return r; }
// a*b complex; 2 VOP3P ops (re-broadcast * b + im-broadcast * (-b.y, b.x))
__device__ __forceinline__ v2f cmul(v2f a, v2f b) {
  v2f re = mk2(a.x, a.x);
  v2f im = mk2(a.y, a.y);
  v2f bs = mk2(-b.y, b.x);
  return re * b + im * bs;
}
__device__ __forceinline__ v2f muli(v2f a) { return mk2(-a.y, a.x); }  // *(+i)

// 8-point inverse DFT (sign +i), DIF, in-place; output slot r holds y[brev3(r)].
__device__ __forceinline__ void idft8(v2f* z) {
  const float C = 0.70710678118654752f;
  v2f t;
  t = z[0]-z[4]; z[0]+=z[4]; z[4]=t;
  t = z[1]-z[5]; z[1]+=z[5]; z[5]=mk2(C*(t.x-t.y), C*(t.x+t.y));
  t = z[2]-z[6]; z[2]+=z[6]; z[6]=muli(t);
  t = z[3]-z[7]; z[3]+=z[7]; z[7]=mk2(-C*(t.x+t.y), C*(t.x-t.y));
  t = z[0]-z[2]; z[0]+=z[2]; z[2]=t;
  t = z[1]-z[3]; z[1]+=z[3]; z[3]=muli(t);
  t = z[4]-z[6]; z[4]+=z[6]; z[6]=t;
  t = z[5]-z[7]; z[5]+=z[7]; z[7]=muli(t);
  t = z[0]-z[1]; z[0]+=z[1]; z[1]=t;
  t = z[2]-z[3]; z[2]+=z[3]; z[3]=t;
  t = z[4]-z[5]; z[4]+=z[5]; z[5]=t;
  t = z[6]-z[7]; z[6]+=z[7]; z[7]=t;
}

__global__ __launch_bounds__(1024, 8) void k_fused(
    const float* __restrict__ sre, const float* __restrict__ sim,
    const float* __restrict__ win, float* __restrict__ out) {
  __shared__ __align__(16) v2f lds2[LDS2N];
  v2f* S = lds2;                       // 16 frame rows, stride FS2

  const int t   = threadIdx.x;
  const int b   = blockIdx.x & 15;
  const int wgq = blockIdx.x >> 4;
  const int f_base = HPW * wgq - 2;    // even
  const int s0     = SPW * wgq;
  const int w  = t >> 6;               // wave id = frame slot
  const int j  = t & 63;               // lane = butterfly index

  // ---- stage spectra: coalesced v2f global loads -> frame-major rows ----
  {
    const v2f* __restrict__ sre2 = (const v2f*)sre + (size_t)b * (FREQ_ * 1024);
    const v2f* __restrict__ sim2 = (const v2f*)sim + (size_t)b * (FREQ_ * 1024);
    const int wp  = t & 7;                       // frame-pair slot
    const int fg0 = f_base + (wp << 1);          // even; validity pair-aligned
    const bool pv = (fg0 >= 0) && (fg0 < FRAMES_);
    const int cb2 = (pv ? fg0 : 0) >> 1;         // safe v2f col
    const int row0 = t >> 3;
#pragma unroll
    for (int k = 0; k < 4; ++k) {
      const int row = row0 + (k << 7);           // 0..511
      const int a   = (row << 10) + cb2;
      v2f re2 = sre2[a];
      v2f im2 = sim2[a];
      if (!pv) { re2 = mk2(0.f, 0.f); im2 = mk2(0.f, 0.f); }
      S[(wp << 1) * FS2 + row]       = mk2(re2.x, im2.x);
      S[((wp << 1) + 1) * FS2 + row] = mk2(re2.y, im2.y);
    }
    if (t < 8) {                                 // row 512 tail
      const int a = (512 << 10) + cb2;
      v2f re2 = sre2[a];
      v2f im2 = sim2[a];
      if (!pv) { re2 = mk2(0.f, 0.f); im2 = mk2(0.f, 0.f); }
      S[(wp << 1) * FS2 + 512]       = mk2(re2.x, im2.x);
      S[((wp << 1) + 1) * FS2 + 512] = mk2(re2.y, im2.y);
    }
  }

  // base twiddles in registers (hidden under staging-load latency)
  v2f pb, tw1b, tw2b;
  {
    float s_, c_;
    __sincosf((float)j * (3.1415926535897932385f / 512.f), &s_, &c_);
    pb = mk2(c_, s_);                    // e^{+i pi j/512}  (PRE base)
    tw1b = cmul(pb, pb);                 // W_512^j = pb^2
    __sincosf((float)(j & 7) * (6.2831853071795864769f / 64.f), &s_, &c_);
    tw2b = mk2(c_, s_);                  // W_64^pos
  }
  __syncthreads();                               // barrier A

  // ================= per-wave FFT (no barriers) =================
  v2f* Zs = S + w * FS2;                 // this wave's private row
  const int brev3[8] = {0, 4, 2, 6, 1, 5, 3, 7};
  // e^{+i pi m/8}, m=0..7 (PRE sub-twiddles, compile-time constants)
  const float URe[8] = {1.f, 0.92387953251f, 0.70710678119f, 0.38268343236f,
                        0.f, -0.38268343236f, -0.70710678119f, -0.92387953251f};
  const float UIm[8] = {0.f, 0.38268343236f, 0.70710678119f, 0.92387953251f,
                        1.f, 0.92387953251f, 0.70710678119f, 0.38268343236f};

  // pass 1 load + E/O fold, register twiddles, packed math
  v2f z[8];
#pragma unroll
  for (int m = 0; m < 8; ++m) {
    const int i = j + (m << 6);
    v2f xa = Zs[i];
    v2f xb = Zs[512 - i];
    if (i == 0) { xa.y = 0.f; xb.y = 0.f; } // irfft ignores Im of bins 0,512
    const v2f bc = mk2(xb.x, -xb.y);        // conj(b)
    const v2f E  = xa + bc;                 // (ar+br, ai-bi)
    const v2f D  = xa - bc;                 // (ar-br, ai+bi)
    const v2f pre = cmul(pb, mk2(URe[m], UIm[m]));  // e^{+i pi (j+64m)/512}
    const v2f O  = cmul(pre, D);
    z[m] = E + muli(O);                     // (Er - Oi, Ei + Or)
  }
  idft8(z);
  // pass 1 write in mp order (r = brev3[mp], involution) with running twiddle
  {
    const int jx = j ^ (j >> 3);
    v2f wacc = tw1b;                     // W_512^{j*1}
#pragma unroll
    for (int mp = 0; mp < 8; ++mp) {
      const int r = brev3[mp];
      const int a = (mp << 6) | (jx ^ (mp << 3));
      if (mp == 0) Zs[a] = z[r];
      else {
        Zs[a] = cmul(z[r], wacc);
        wacc = cmul(wacc, tw1b);
      }
    }
  }
  LGKM_SYNC();
  // pass 2 (s_read = blk*64 + m*8 + pos; s_write = blk*64 + mp*8 + pos)
  const int pos = j & 7, blk = j >> 3;
  {
#pragma unroll
    for (int m = 0; m < 8; ++m) {
      const int a = (blk << 6) | (((m << 3) | pos) ^ ((blk << 3) | m));
      z[m] = Zs[a];
    }
    idft8(z);
    v2f wacc = tw2b;                     // W_64^{pos*1}
#pragma unroll
    for (int mp = 0; mp < 8; ++mp) {
      const int r = brev3[mp];
      const int a = (blk << 6) | (((mp << 3) | pos) ^ ((blk << 3) | mp));
      if (mp == 0) Zs[a] = z[r];
      else {
        Zs[a] = cmul(z[r], wacc);
        wacc = cmul(wacc, tw2b);
      }
    }
  }
  LGKM_SYNC();
  // pass 3 (s = j*8 + m -> a = ((j<<3)^j) ^ m), final butterfly, twiddle-free
  v2f y[8];
  {
    const int b3 = (j << 3) ^ j;
#pragma unroll
    for (int m = 0; m < 8; ++m) y[m] = Zs[b3 ^ m];
  }
  idft8(y);
  // write RAW time pairs interleaved: pair mt holds (x[2mt], x[2mt+1]);
  // mt = brev3(r)*64 + c. Natural consecutive addresses -> conflict-free b64.
  {
    const int c = ((j & 7) << 3) | (j >> 3);      // Stockham output perm
#pragma unroll
    for (int r = 0; r < 8; ++r) {
      const int mt = (brev3[r] << 6) | c;
      Zs[mt] = y[r];
    }
  }
  __syncthreads();                               // barrier B

  // ---- overlap-add with register-computed window + coalesced store ----
  // win[n] = 0.5 - 0.5 cos(pi n/512); tap jj angle = pi*me0/256 + jj*pi/2.
  // kk2 folds 0.5(window) * 0.5/512 (ifft+E/O norm) * 2/3 (COLA interior).
  float* __restrict__ outb = out + (size_t)b * T_OUT_;
  const int uA  = s0 + (t << 1) + PAD_;
  const int me0 = (uA & 255) >> 1;     // identical for both rr iterations
  v2f wp4[4];
  {
    float sme, cme;
    __sincosf((float)me0 * (3.1415926535897932385f / 256.f), &sme, &cme);
    const v2f wb = mk2(cme, sme);                       // e^{i pi me0/256}
    const v2f wo = cmul(wb, mk2(0.99998117528f, 0.0061358846492f)); // * e^{i pi/512}
    const float kk2 = (0.25f / 512.0f) * 0.66666666666666667f;
    wp4[0] = mk2(kk2 - kk2 * wb.x, kk2 - kk2 * wo.x);   // jj=0: cos=+Re
    wp4[1] = mk2(kk2 + kk2 * wb.y, kk2 + kk2 * wo.y);   // jj=1: cos=-Im
    wp4[2] = mk2(kk2 + kk2 * wb.x, kk2 + kk2 * wo.x);   // jj=2: cos=-Re
    wp4[3] = mk2(kk2 - kk2 * wb.y, kk2 - kk2 * wo.y);   // jj=3: cos=+Im
  }
#pragma unroll
  for (int rr = 0; rr < 2; ++rr) {
    const int idx = t + (rr << 10);    // 0..1535 used
    if (idx < 1536) {
      const int s = s0 + (idx << 1);
      if (s < T_OUT_) {
        const int u  = s + PAD_;
        const int fh = u >> 8;
        v2f acc = mk2(0.f, 0.f);
#pragma unroll
        for (int jj = 0; jj < 4; ++jj) {
          const int fl = fh - jj - f_base;  // 0..15 by construction
          const v2f tap = S[fl * FS2 + (jj << 7) + me0];
          acc += tap * wp4[jj];
        }
        if (u >= 768 && u <= T_OUT_ - 2) {  // full-overlap interior
          *(v2f*)(outb + s) = acc;
        } else {                            // edge samples: exact envelope
          float iv[2];
#pragma unroll
          for (int h = 0; h < 2; ++h) {
            const int uu  = u + h;
            const int fh2 = min(FRAMES_ - 1, uu >> 8);
            const int fl2 = (uu >= 1024) ? (((uu - 1024) >> 8) + 1) : 0;
            float e = 0.f;
            for (int ff = fl2; ff <= fh2; ++ff) {
              const float ww = win[uu - (ff << 8)];
              e += ww * ww;
            }
            iv[h] = 1.5f / e;               // 1.5 compensates folded 2/3
          }
          *(v2f*)(outb + s) = mk2(acc.x * iv[0], acc.y * iv[1]);
        }
      }
    }
  }
}

extern "C" void kernel_launch(void* const* d_in, const int* in_sizes, int n_in,
                              void* d_out, int out_size, void* d_ws, size_t ws_size,
                              hipStream_t stream) {
  (void)in_sizes; (void)n_in; (void)out_size; (void)d_ws; (void)ws_size;
  const float* sre = (const float*)d_in[0];
  const float* sim = (const float*)d_in[1];
  const float* win = (const float*)d_in[2];
  float* out = (float*)d_out;
  k_fused<<<B_ * NCHUNK, 1024, 0, stream>>>(sre, sim, win, out);
}